// Round 21
// baseline (120.739 us; speedup 1.0000x reference)
//
#include <hip/hip_runtime.h>
#include <math.h>

#define SEQ    2048
#define DMODEL 1024
#define NHEADS 16
#define DHEAD  64
#define NBATCH 2

typedef __attribute__((ext_vector_type(8)))  short bf16x8;
typedef __attribute__((ext_vector_type(4)))  float f32x4;
typedef __attribute__((ext_vector_type(16))) float f32x16;

__device__ __forceinline__ unsigned short f2bf(float f) {
    union { float f; unsigned u; } v; v.f = f;
    unsigned r = (v.u + 0x7FFF + ((v.u >> 16) & 1)) >> 16;
    return (unsigned short)r;
}

__device__ __forceinline__ unsigned cvt_pk_bf16(float lo, float hi) {
    unsigned r;
    asm("v_cvt_pk_bf16_f32 %0, %1, %2" : "=v"(r) : "v"(lo), "v"(hi));
    return r;
}

// async global->LDS, 16B per lane
__device__ __forceinline__ void gload16(const void* g, void* l) {
    __builtin_amdgcn_global_load_lds(
        (const __attribute__((address_space(1))) unsigned*)g,
        (__attribute__((address_space(3))) unsigned*)l, 16, 0, 0);
}

// ---------------------------------------------------------------------------
// Merged prep: blocks 0..2047 cast hidden states fp32->bf16 (8 elems/thr);
// blocks 2048..3071 transpose-cast the four weights [K][N] -> bf16 [N][K].
// ---------------------------------------------------------------------------
__global__ __launch_bounds__(256)
void prep_cast_kernel(const float* __restrict__ hs,
                      const float* __restrict__ W0, const float* __restrict__ W1,
                      const float* __restrict__ W2, const float* __restrict__ W3,
                      unsigned short* __restrict__ hs_bf,
                      unsigned short* __restrict__ Wt_out) {
    __shared__ float tile[64][65];
    const int bid = blockIdx.x;
    const int tid = threadIdx.x;

    if (bid < 2048) {
        const size_t g8 = ((size_t)bid * 256 + tid) * 8;
        float4 a = *reinterpret_cast<const float4*>(hs + g8);
        float4 b = *reinterpret_cast<const float4*>(hs + g8 + 4);
        bf16x8 o;
        o[0] = (short)f2bf(a.x); o[1] = (short)f2bf(a.y);
        o[2] = (short)f2bf(a.z); o[3] = (short)f2bf(a.w);
        o[4] = (short)f2bf(b.x); o[5] = (short)f2bf(b.y);
        o[6] = (short)f2bf(b.z); o[7] = (short)f2bf(b.w);
        *reinterpret_cast<bf16x8*>(hs_bf + g8) = o;
        return;
    }

    const int i    = bid - 2048;          // 0..1023
    const int wsel = i >> 8;              // 0..3
    const float* W = (wsel == 0) ? W0 : (wsel == 1) ? W1 : (wsel == 2) ? W2 : W3;
    unsigned short* Wt = Wt_out + (size_t)wsel * 1024 * 1024;
    const int nt = i & 15;
    const int kt = (i >> 4) & 15;

#pragma unroll
    for (int r = 0; r < 4; ++r) {
        int kl = r * 16 + (tid >> 4);
        int nl = (tid & 15) * 4;
        float4 v = *reinterpret_cast<const float4*>(
            &W[(size_t)(kt * 64 + kl) * 1024 + nt * 64 + nl]);
        tile[kl][nl + 0] = v.x; tile[kl][nl + 1] = v.y;
        tile[kl][nl + 2] = v.z; tile[kl][nl + 3] = v.w;
    }
    __syncthreads();

    const int n  = tid >> 2;
    const int kc = (tid & 3) * 16;
    bf16x8 o0, o1;
#pragma unroll
    for (int i2 = 0; i2 < 8; ++i2) o0[i2] = (short)f2bf(tile[kc + i2][n]);
#pragma unroll
    for (int i2 = 0; i2 < 8; ++i2) o1[i2] = (short)f2bf(tile[kc + 8 + i2][n]);
    unsigned short* op = Wt + (size_t)(nt * 64 + n) * 1024 + kt * 64 + kc;
    *reinterpret_cast<bf16x8*>(op)     = o0;
    *reinterpret_cast<bf16x8*>(op + 8) = o1;
}

// ---------------------------------------------------------------------------
// Transpose V: bf16 [B,H,S,64] -> bf16 [B,H,64,S] via 64x64 LDS tiles.
// (R20's fused-V-store variant reverted: it cost more inside the QKV kernel
//  than this standalone kernel does.)
// ---------------------------------------------------------------------------
__global__ __launch_bounds__(256)
void vt_kernel(const unsigned short* __restrict__ Vh, unsigned short* __restrict__ Vt) {
    __shared__ unsigned short tile[64][72];
    const int bid = blockIdx.x;           // 0..1023
    const int st  = bid & 31;             // s-tile
    const int bh  = bid >> 5;             // 0..31
    const int s0  = st * 64;
    const int tid = threadIdx.x;

    const int sl = tid >> 2;
    const int dc = (tid & 3) * 16;
    const unsigned short* src = Vh + ((size_t)bh * SEQ + s0 + sl) * 64 + dc;
    *reinterpret_cast<bf16x8*>(&tile[sl][dc])     = *reinterpret_cast<const bf16x8*>(src);
    *reinterpret_cast<bf16x8*>(&tile[sl][dc + 8]) = *reinterpret_cast<const bf16x8*>(src + 8);
    __syncthreads();

    const int dl = tid >> 2;
    const int sc = (tid & 3) * 16;
    unsigned short tmp[16];
#pragma unroll
    for (int k2 = 0; k2 < 16; ++k2) tmp[k2] = tile[sc + k2][dl];
    unsigned short* dst = Vt + ((size_t)bh * 64 + dl) * SEQ + s0 + sc;
    *reinterpret_cast<bf16x8*>(dst)     = *reinterpret_cast<bf16x8*>(&tmp[0]);
    *reinterpret_cast<bf16x8*>(dst + 8) = *reinterpret_cast<bf16x8*>(&tmp[8]);
}

// ---------------------------------------------------------------------------
// QKV bf16 MFMA GEMM (R19 proven): 128x128, BK=32, gload_lds(16B), double-
// buffered LDS, 2-phase, chunk-XOR swizzle, XCD-rect remap, LDS-staged
// head-major epilogue (full-line stores).
// ---------------------------------------------------------------------------
__global__ __launch_bounds__(256)
void gemm_qkv(const unsigned short* __restrict__ A,
              const unsigned short* __restrict__ Bt,
              const float* __restrict__ bias0, const float* __restrict__ bias1,
              const float* __restrict__ bias2,
              unsigned short* __restrict__ Qo, unsigned short* __restrict__ Ko,
              unsigned short* __restrict__ Vo) {
    __shared__ unsigned short SM[4][128 * 32];   // A bufs [0..1], B bufs [2..3]
    const int K = 1024;

    int bx, by;
    {
        const int xcd = blockIdx.x & 7, i = blockIdx.x >> 3;
        bx = (xcd >> 2) * 12 + i % 12;       // grid 24x32 -> per-XCD 12x8 rect
        by = (xcd & 3) * 8 + i / 12;
    }
    const int tid  = threadIdx.x;
    const int bm   = by * 128;
    const int bn   = bx * 128;
    const int w    = tid >> 6;
    const int lane = tid & 63;
    const int lrow = lane & 15;
    const int lk   = lane >> 4;
    const int wm0  = (w >> 1) * 64;
    const int wn0  = (w & 1) * 64;

    const int boff0 = tid * 16;
    const int boff1 = 4096 + tid * 16;
    const int row0  = tid >> 2;
    const int row1  = 64 + row0;
    const int c     = tid & 3;
    const int sw0   = (c ^ ((row0 >> 1) & 3)) * 8;
    const int sw1   = (c ^ ((row1 >> 1) & 3)) * 8;

    const unsigned short* Ag = A  + (size_t)bm * K;
    const unsigned short* Bg = Bt + (size_t)bn * K;

    f32x4 acc[4][4];
#pragma unroll
    for (int i = 0; i < 4; ++i)
#pragma unroll
        for (int j = 0; j < 4; ++j) acc[i][j] = (f32x4){0.f, 0.f, 0.f, 0.f};

    const int NT = K / 32;
    gload16(Ag + (size_t)row0 * K + sw0, (char*)&SM[0][0] + boff0);
    gload16(Ag + (size_t)row1 * K + sw1, (char*)&SM[0][0] + boff1);
    gload16(Bg + (size_t)row0 * K + sw0, (char*)&SM[2][0] + boff0);
    gload16(Bg + (size_t)row1 * K + sw1, (char*)&SM[2][0] + boff1);
    __syncthreads();

    int buf = 0;
    for (int kt = 0; kt < NT; ++kt) {
        if (kt + 1 < NT) {
            const int k0 = (kt + 1) * 32;
            gload16(Ag + (size_t)row0 * K + k0 + sw0, (char*)&SM[buf ^ 1][0] + boff0);
            gload16(Ag + (size_t)row1 * K + k0 + sw1, (char*)&SM[buf ^ 1][0] + boff1);
            gload16(Bg + (size_t)row0 * K + k0 + sw0, (char*)&SM[2 + (buf ^ 1)][0] + boff0);
            gload16(Bg + (size_t)row1 * K + k0 + sw1, (char*)&SM[2 + (buf ^ 1)][0] + boff1);
        }

        bf16x8 af[4], bf[4];
#pragma unroll
        for (int mg = 0; mg < 4; ++mg) {
            const int r = wm0 + mg * 16 + lrow;
            af[mg] = *reinterpret_cast<const bf16x8*>(
                (char*)&SM[buf][0] + r * 64 + ((lk ^ ((r >> 1) & 3)) * 16));
        }
#pragma unroll
        for (int ng = 0; ng < 4; ++ng) {
            const int r = wn0 + ng * 16 + lrow;
            bf[ng] = *reinterpret_cast<const bf16x8*>(
                (char*)&SM[2 + buf][0] + r * 64 + ((lk ^ ((r >> 1) & 3)) * 16));
        }
#pragma unroll
        for (int mg = 0; mg < 4; ++mg)
#pragma unroll
            for (int ng = 0; ng < 4; ++ng)
                acc[mg][ng] = __builtin_amdgcn_mfma_f32_16x16x32_bf16(
                    af[mg], bf[ng], acc[mg][ng], 0, 0, 0);

        __syncthreads();
        buf ^= 1;
    }

    const int type = bn >> 10;                 // 0=Q 1=K 2=V (uniform/block)
    const int nloc = bn & 1023;
    const float* bias = (type == 0) ? bias0 : (type == 1) ? bias1 : bias2;
    unsigned short* dst = (type == 0) ? Qo : (type == 1) ? Ko : Vo;
    const float scale = (type == 0) ? (0.125f * 1.44269504088896f) : 1.0f;
    char* cst = (char*)&SM[0][0];              // 32KB C tile

    // deposit head-major tile [r][ctl], 16B-granule XOR swizzle
#pragma unroll
    for (int ng = 0; ng < 4; ++ng) {
        const int ctl = wn0 + ng * 16 + lrow;
        const float bv = bias[nloc + ctl];
        const int byte = ctl * 2;
#pragma unroll
        for (int mg = 0; mg < 4; ++mg) {
#pragma unroll
            for (int j = 0; j < 4; ++j) {
                const int r = wm0 + mg * 16 + lk * 4 + j;
                const int addr = r * 256 + (((byte >> 4) ^ (r & 7)) << 4) + (byte & 15);
                *reinterpret_cast<unsigned short*>(cst + addr)
                    = f2bf((acc[mg][ng][j] + bv) * scale);
            }
        }
    }
    __syncthreads();
    // full-line stores: 8 lanes cover one 128B output line
    const int bb = bm >> 11;
    const int s0 = bm & 2047;
    const int h0 = nloc >> 6;
#pragma unroll
    for (int it = 0; it < 8; ++it) {
        const int hh = it >> 2;
        const int r  = (it & 3) * 32 + (tid >> 3);
        const int cc = tid & 7;
        const int addr = r * 256 + ((((hh * 8 + cc)) ^ (r & 7)) << 4);
        bf16x8 vals = *reinterpret_cast<const bf16x8*>(cst + addr);
        unsigned short* p = dst
            + ((size_t)(bb * 16 + h0 + hh) * SEQ + s0 + r) * 64 + cc * 8;
        *reinterpret_cast<bf16x8*>(p) = vals;
    }
}

// ---------------------------------------------------------------------------
// O-projection GEMM, R21: 128x64 tiles -> grid 512 = 2 blocks/CU (was 256 =
// 1/CU with zero inter-block latency hiding). 256 thr, waves 2x2 over 64x32
// sub-tiles, acc[4][2]. LDS 24KB (A 2x8KB + B 2x4KB). Same 2-phase pipeline,
// chunk-XOR swizzle, XCD-rect remap (per-XCD 4bx x 16by).
// ---------------------------------------------------------------------------
__global__ __launch_bounds__(256)
void gemm_oproj(const unsigned short* __restrict__ A,
                const unsigned short* __restrict__ Bt,
                const float* __restrict__ bias0,
                float* __restrict__ Cf) {
    __shared__ unsigned short As[2][128 * 32];   // 16KB
    __shared__ unsigned short Bs[2][64 * 32];    // 8KB
    const int K = 1024, N = 1024;

    int bx, by;
    {
        const int xcd = blockIdx.x & 7, i = blockIdx.x >> 3;   // i 0..63
        bx = (xcd & 3) * 4 + i % 4;          // 0..15 (N/64)
        by = (xcd >> 2) * 16 + i / 4;        // 0..31 (M/128)
    }
    const int tid  = threadIdx.x;
    const int bm   = by * 128;
    const int bn   = bx * 64;
    const int w    = tid >> 6;
    const int lane = tid & 63;
    const int lrow = lane & 15;
    const int lk   = lane >> 4;
    const int wm0  = (w >> 1) * 64;
    const int wn0  = (w & 1) * 32;

    // A staging (two gloads), B staging (one gload)
    const int boff0 = tid * 16;
    const int boff1 = 4096 + tid * 16;
    const int row0  = tid >> 2;              // 0..63
    const int row1  = 64 + row0;
    const int c     = tid & 3;
    const int swA0  = (c ^ ((row0 >> 1) & 3)) * 8;
    const int swA1  = (c ^ ((row1 >> 1) & 3)) * 8;
    const int swB0  = (c ^ ((row0 >> 1) & 3)) * 8;   // B rows 0..63 same pattern

    const unsigned short* Ag = A  + (size_t)bm * K;
    const unsigned short* Bg = Bt + (size_t)bn * K;

    f32x4 acc[4][2];
#pragma unroll
    for (int i = 0; i < 4; ++i)
#pragma unroll
        for (int j = 0; j < 2; ++j) acc[i][j] = (f32x4){0.f, 0.f, 0.f, 0.f};

    const int NT = K / 32;
    gload16(Ag + (size_t)row0 * K + swA0, (char*)&As[0][0] + boff0);
    gload16(Ag + (size_t)row1 * K + swA1, (char*)&As[0][0] + boff1);
    gload16(Bg + (size_t)row0 * K + swB0, (char*)&Bs[0][0] + boff0);
    __syncthreads();

    int buf = 0;
    for (int kt = 0; kt < NT; ++kt) {
        if (kt + 1 < NT) {
            const int k0 = (kt + 1) * 32;
            gload16(Ag + (size_t)row0 * K + k0 + swA0, (char*)&As[buf ^ 1][0] + boff0);
            gload16(Ag + (size_t)row1 * K + k0 + swA1, (char*)&As[buf ^ 1][0] + boff1);
            gload16(Bg + (size_t)row0 * K + k0 + swB0, (char*)&Bs[buf ^ 1][0] + boff0);
        }

        bf16x8 af[4], bf[2];
#pragma unroll
        for (int mg = 0; mg < 4; ++mg) {
            const int r = wm0 + mg * 16 + lrow;
            af[mg] = *reinterpret_cast<const bf16x8*>(
                (char*)&As[buf][0] + r * 64 + ((lk ^ ((r >> 1) & 3)) * 16));
        }
#pragma unroll
        for (int ng = 0; ng < 2; ++ng) {
            const int r = wn0 + ng * 16 + lrow;
            bf[ng] = *reinterpret_cast<const bf16x8*>(
                (char*)&Bs[buf][0] + r * 64 + ((lk ^ ((r >> 1) & 3)) * 16));
        }
#pragma unroll
        for (int mg = 0; mg < 4; ++mg)
#pragma unroll
            for (int ng = 0; ng < 2; ++ng)
                acc[mg][ng] = __builtin_amdgcn_mfma_f32_16x16x32_bf16(
                    af[mg], bf[ng], acc[mg][ng], 0, 0, 0);

        __syncthreads();
        buf ^= 1;
    }

#pragma unroll
    for (int ng = 0; ng < 2; ++ng) {
        const int col = bn + wn0 + ng * 16 + lrow;
        const float bv = bias0[col];
#pragma unroll
        for (int mg = 0; mg < 4; ++mg) {
#pragma unroll
            for (int j = 0; j < 4; ++j) {
                const int row = bm + wm0 + mg * 16 + lk * 4 + j;
                Cf[(size_t)row * N + col] = acc[mg][ng][j] + bv;
            }
        }
    }
}

// ---------------------------------------------------------------------------
// Causal flash attention (R17/R19 version, 45.7us proven): swapped-operand
// 32x32x16 MFMA, 128-key chunks with 2 subtiles/barrier, exp2 softmax with
// T13 defer-rescale, XCD head-grouping + constant-sum pairing.
// ---------------------------------------------------------------------------
__global__ __launch_bounds__(256)
void attn_mfma_kernel(const unsigned short* __restrict__ Qg,
                      const unsigned short* __restrict__ Kg,
                      const unsigned short* __restrict__ Vtg,
                      unsigned short* __restrict__ CTX) {
    __shared__ __align__(16) unsigned short Ks[2][2][64 * 64];
    __shared__ __align__(16) unsigned short Vt[2][2][64 * 64];

    const int bid = blockIdx.x;           // 0..511
    const int xcd = bid & 7;
    const int s   = bid >> 3;             // 0..63
    const int bh  = xcd * 4 + (s & 3);    // 4 heads per XCD
    const int k2  = s >> 2;               // 0..15
    const int rb  = (k2 < 8) ? k2 : (23 - k2);   // pair (k2,k2+8) -> (a,15-a)
    const int b  = bh >> 4;
    const int h  = bh & 15;
    const int r0 = rb * 128;
    const int tid  = threadIdx.x;
    const int w    = tid >> 6;
    const int lane = tid & 63;
    const int qcol = lane & 31;
    const int hlf  = lane >> 5;
    const int wr0  = r0 + w * 32;
    const int qrow = wr0 + qcol;

    const unsigned short* Kb = Kg + ((size_t)bh * SEQ) * DHEAD;
    const unsigned short* Vb = Vtg + ((size_t)bh * DHEAD) * SEQ;

    bf16x8 qf[4];
    {
        const unsigned short* qp = Qg + ((size_t)bh * SEQ + qrow) * DHEAD + hlf * 8;
#pragma unroll
        for (int ksub = 0; ksub < 4; ++ksub)
            qf[ksub] = *reinterpret_cast<const bf16x8*>(qp + ksub * 16);
    }

    f32x16 O0, O1;
#pragma unroll
    for (int r = 0; r < 16; ++r) { O0[r] = 0.f; O1[r] = 0.f; }
    float m = -1e30f, l = 0.f;

    const int srow = tid >> 2;
    const int c0   = (tid & 3) * 16;
    const int sb0  = srow * 128 + ((c0 * 2) ^ ((srow & 7) << 4));
    const int sb1  = srow * 128 + (((c0 + 8) * 2) ^ ((srow & 7) << 4));

    bf16x8 rk00, rk01, rk10, rk11, rv00, rv01, rv10, rv11;
    {
        const unsigned short* kp0 = Kb + (size_t)srow * DHEAD + c0;
        const unsigned short* kp1 = Kb + (size_t)(64 + srow) * DHEAD + c0;
        const unsigned short* vp  = Vb + (size_t)srow * SEQ + c0;
        rk00 = *reinterpret_cast<const bf16x8*>(kp0);
        rk01 = *reinterpret_cast<const bf16x8*>(kp0 + 8);
        rk10 = *reinterpret_cast<const bf16x8*>(kp1);
        rk11 = *reinterpret_cast<const bf16x8*>(kp1 + 8);
        rv00 = *reinterpret_cast<const bf16x8*>(vp);
        rv01 = *reinterpret_cast<const bf16x8*>(vp + 8);
        rv10 = *reinterpret_cast<const bf16x8*>(vp + 64);
        rv11 = *reinterpret_cast<const bf16x8*>(vp + 64 + 8);
    }

    const int nch = rb + 1;               // 128-key chunks
    for (int ch = 0; ch < nch; ++ch) {
        const int jc  = ch * 128;
        const int buf = ch & 1;
        {
            char* k0 = (char*)&Ks[buf][0][0];
            char* k1 = (char*)&Ks[buf][1][0];
            char* v0 = (char*)&Vt[buf][0][0];
            char* v1 = (char*)&Vt[buf][1][0];
            *reinterpret_cast<bf16x8*>(k0 + sb0) = rk00;
            *reinterpret_cast<bf16x8*>(k0 + sb1) = rk01;
            *reinterpret_cast<bf16x8*>(k1 + sb0) = rk10;
            *reinterpret_cast<bf16x8*>(k1 + sb1) = rk11;
            *reinterpret_cast<bf16x8*>(v0 + sb0) = rv00;
            *reinterpret_cast<bf16x8*>(v0 + sb1) = rv01;
            *reinterpret_cast<bf16x8*>(v1 + sb0) = rv10;
            *reinterpret_cast<bf16x8*>(v1 + sb1) = rv11;
        }
        __syncthreads();
        if (ch + 1 < nch) {
            const int j1 = jc + 128;
            const unsigned short* kp0 = Kb + (size_t)(j1 + srow) * DHEAD + c0;
            const unsigned short* kp1 = Kb + (size_t)(j1 + 64 + srow) * DHEAD + c0;
            const unsigned short* vp  = Vb + (size_t)srow * SEQ + j1 + c0;
            rk00 = *reinterpret_cast<const bf16x8*>(kp0);
            rk01 = *reinterpret_cast<const bf16x8*>(kp0 + 8);
            rk10 = *reinterpret_cast<const bf16x8*>(kp1);
            rk11 = *reinterpret_cast<const bf16x8*>(kp1 + 8);
            rv00 = *reinterpret_cast<const bf16x8*>(vp);
            rv01 = *reinterpret_cast<const bf16x8*>(vp + 8);
            rv10 = *reinterpret_cast<const bf16x8*>(vp + 64);
            rv11 = *reinterpret_cast<const bf16x8*>(vp + 64 + 8);
        }

#pragma unroll
        for (int st = 0; st < 2; ++st) {
            const int j0 = jc + st * 64;
            if (j0 <= wr0 + 31) {
                const char* KB = (const char*)&Ks[buf][st][0];
                const char* VB = (const char*)&Vt[buf][st][0];
                f32x16 S[2];
#pragma unroll
                for (int r = 0; r < 16; ++r) { S[0][r] = 0.f; S[1][r] = 0.f; }
                __builtin_amdgcn_s_setprio(1);
#pragma unroll
                for (int kb = 0; kb < 2; ++kb) {
                    const int key = kb * 32 + qcol;
#pragma unroll
                    for (int ksub = 0; ksub < 4; ++ksub) {
                        int boff = key * 128 + ((ksub * 32 + hlf * 16) ^ ((key & 7) << 4));
                        bf16x8 kf = *reinterpret_cast<const bf16x8*>(KB + boff);
                        S[kb] = __builtin_amdgcn_mfma_f32_32x32x16_bf16(
                            kf, qf[ksub], S[kb], 0, 0, 0);
                    }
                }
                __builtin_amdgcn_s_setprio(0);

                if (j0 + 63 > wr0) {
#pragma unroll
                    for (int kb = 0; kb < 2; ++kb)
#pragma unroll
                        for (int r = 0; r < 16; ++r) {
                            int ka = j0 + kb * 32 + (r & 3) + 8 * (r >> 2) + 4 * hlf;
                            if (ka > qrow) S[kb][r] = -1e30f;
                        }
                }

                float mx[8];
#pragma unroll
                for (int r = 0; r < 8; ++r)
                    mx[r] = fmaxf(fmaxf(S[0][r], S[0][r + 8]),
                                  fmaxf(S[1][r], S[1][r + 8]));
                float m01 = fmaxf(mx[0], mx[1]), m23 = fmaxf(mx[2], mx[3]);
                float m45 = fmaxf(mx[4], mx[5]), m67 = fmaxf(mx[6], mx[7]);
                float pm = fmaxf(fmaxf(m01, m23), fmaxf(m45, m67));
                pm = fmaxf(pm, __shfl_xor(pm, 32));

                if (!__all(pm <= m + 8.f)) {
                    float mnew = fmaxf(m, pm);
                    float cor  = __builtin_amdgcn_exp2f(m - mnew);
                    m = mnew;
                    l *= cor;
#pragma unroll
                    for (int r = 0; r < 16; ++r) { O0[r] *= cor; O1[r] *= cor; }
                }

                float l0 = 0.f, l1 = 0.f, l2 = 0.f, l3 = 0.f;
#pragma unroll
                for (int kb = 0; kb < 2; ++kb)
#pragma unroll
                    for (int r = 0; r < 16; r += 4) {
                        float p0 = __builtin_amdgcn_exp2f(S[kb][r + 0] - m);
                        float p1 = __builtin_amdgcn_exp2f(S[kb][r + 1] - m);
                        float p2 = __builtin_amdgcn_exp2f(S[kb][r + 2] - m);
                        float p3 = __builtin_amdgcn_exp2f(S[kb][r + 3] - m);
                        S[kb][r + 0] = p0; S[kb][r + 1] = p1;
                        S[kb][r + 2] = p2; S[kb][r + 3] = p3;
                        l0 += p0; l1 += p1; l2 += p2; l3 += p3;
                    }
                l += (l0 + l1) + (l2 + l3);

#pragma unroll
                for (int kc = 0; kc < 4; ++kc) {
                    const int kb = kc >> 1;
                    const int R0 = (kc & 1) * 8;
                    unsigned pa = cvt_pk_bf16(S[kb][R0 + 0], S[kb][R0 + 1]);
                    unsigned pc = cvt_pk_bf16(S[kb][R0 + 4], S[kb][R0 + 5]);
                    asm("v_permlane32_swap_b32 %0, %1" : "+v"(pa), "+v"(pc));
                    unsigned pb = cvt_pk_bf16(S[kb][R0 + 2], S[kb][R0 + 3]);
                    unsigned pd = cvt_pk_bf16(S[kb][R0 + 6], S[kb][R0 + 7]);
                    asm("v_permlane32_swap_b32 %0, %1" : "+v"(pb), "+v"(pd));
                    union { unsigned u[4]; bf16x8 v; } pf;
                    pf.u[0] = pa; pf.u[1] = pb; pf.u[2] = pc; pf.u[3] = pd;
                    __builtin_amdgcn_s_setprio(1);
#pragma unroll
                    for (int db = 0; db < 2; ++db) {
                        const int dim = db * 32 + qcol;
                        int boff = dim * 128 + ((kc * 32 + hlf * 16) ^ ((dim & 7) << 4));
                        bf16x8 vf = *reinterpret_cast<const bf16x8*>(VB + boff);
                        if (db == 0)
                            O0 = __builtin_amdgcn_mfma_f32_32x32x16_bf16(vf, pf.v, O0, 0, 0, 0);
                        else
                            O1 = __builtin_amdgcn_mfma_f32_32x32x16_bf16(vf, pf.v, O1, 0, 0, 0);
                    }
                    __builtin_amdgcn_s_setprio(0);
                }
            }
        }
    }

    l += __shfl_xor(l, 32);
    const float inv = 1.f / l;
    unsigned short* crow = CTX + ((size_t)(b * SEQ + qrow)) * DMODEL + h * DHEAD;
#pragma unroll
    for (int pq = 0; pq < 4; ++pq) {
        unsigned w0 = cvt_pk_bf16(O0[pq * 4 + 0] * inv, O0[pq * 4 + 1] * inv);
        unsigned w1 = cvt_pk_bf16(O0[pq * 4 + 2] * inv, O0[pq * 4 + 3] * inv);
        uint2 val; val.x = w0; val.y = w1;
        *reinterpret_cast<uint2*>(crow + 8 * pq + 4 * hlf) = val;
    }
#pragma unroll
    for (int pq = 0; pq < 4; ++pq) {
        unsigned w0 = cvt_pk_bf16(O1[pq * 4 + 0] * inv, O1[pq * 4 + 1] * inv);
        unsigned w1 = cvt_pk_bf16(O1[pq * 4 + 2] * inv, O1[pq * 4 + 3] * inv);
        uint2 val; val.x = w0; val.y = w1;
        *reinterpret_cast<uint2*>(crow + 32 + 8 * pq + 4 * hlf) = val;
    }
}

// ---------------------------------------------------------------------------
extern "C" void kernel_launch(void* const* d_in, const int* in_sizes, int n_in,
                              void* d_out, int out_size, void* d_ws, size_t ws_size,
                              hipStream_t stream) {
    const float* hs = (const float*)d_in[0];
    const float* Wq = (const float*)d_in[1];
    const float* bq = (const float*)d_in[2];
    const float* Wk = (const float*)d_in[3];
    const float* bk = (const float*)d_in[4];
    const float* Wv = (const float*)d_in[5];
    const float* bv = (const float*)d_in[6];
    const float* Wo = (const float*)d_in[7];
    const float* bo = (const float*)d_in[8];
    float* out = (float*)d_out;

    const size_t NTOK = (size_t)NBATCH * SEQ;        // 4096
    unsigned short* hs_bf  = (unsigned short*)d_ws;              // 8 MB
    unsigned short* Wqkv_t = hs_bf + NTOK * DMODEL;              // 6 MB [3072][1024]
    unsigned short* Wo_t   = Wqkv_t + 3072 * 1024;               // 2 MB [1024][1024]
    unsigned short* Qh     = Wo_t + 1024 * 1024;                 // 8 MB [B,H,S,64]
    unsigned short* Kh     = Qh + NTOK * DMODEL;                 // 8 MB
    unsigned short* Vh     = Kh + NTOK * DMODEL;                 // 8 MB [B,H,S,64]
    unsigned short* Vt     = Vh + NTOK * DMODEL;                 // 8 MB [B,H,64,S]
    unsigned short* Cb     = Vt + NTOK * DMODEL;                 // 8 MB ctx bf16

    prep_cast_kernel<<<3072, 256, 0, stream>>>(hs, Wq, Wk, Wv, Wo, hs_bf, Wqkv_t);

    gemm_qkv<<<768, 256, 0, stream>>>(hs_bf, Wqkv_t, bq, bk, bv, Qh, Kh, Vh);

    vt_kernel<<<1024, 256, 0, stream>>>(Vh, Vt);

    attn_mfma_kernel<<<NBATCH * NHEADS * (SEQ / 128), 256, 0, stream>>>(Qh, Kh, Vt, Cb);

    gemm_oproj<<<512, 256, 0, stream>>>(Cb, Wo_t, bo, out);
}

// Round 22
// 113.783 us; speedup vs baseline: 1.0611x; 1.0611x over previous
//
#include <hip/hip_runtime.h>
#include <math.h>

#define SEQ    2048
#define DMODEL 1024
#define NHEADS 16
#define DHEAD  64
#define NBATCH 2

typedef __attribute__((ext_vector_type(8)))  short bf16x8;
typedef __attribute__((ext_vector_type(4)))  float f32x4;
typedef __attribute__((ext_vector_type(16))) float f32x16;

__device__ __forceinline__ unsigned short f2bf(float f) {
    union { float f; unsigned u; } v; v.f = f;
    unsigned r = (v.u + 0x7FFF + ((v.u >> 16) & 1)) >> 16;
    return (unsigned short)r;
}

__device__ __forceinline__ unsigned cvt_pk_bf16(float lo, float hi) {
    unsigned r;
    asm("v_cvt_pk_bf16_f32 %0, %1, %2" : "=v"(r) : "v"(lo), "v"(hi));
    return r;
}

// async global->LDS, 16B per lane
__device__ __forceinline__ void gload16(const void* g, void* l) {
    __builtin_amdgcn_global_load_lds(
        (const __attribute__((address_space(1))) unsigned*)g,
        (__attribute__((address_space(3))) unsigned*)l, 16, 0, 0);
}

// ---------------------------------------------------------------------------
// Merged prep: blocks 0..2047 cast hidden states fp32->bf16 (8 elems/thr);
// blocks 2048..3071 transpose-cast the four weights [K][N] -> bf16 [N][K].
// ---------------------------------------------------------------------------
__global__ __launch_bounds__(256)
void prep_cast_kernel(const float* __restrict__ hs,
                      const float* __restrict__ W0, const float* __restrict__ W1,
                      const float* __restrict__ W2, const float* __restrict__ W3,
                      unsigned short* __restrict__ hs_bf,
                      unsigned short* __restrict__ Wt_out) {
    __shared__ float tile[64][65];
    const int bid = blockIdx.x;
    const int tid = threadIdx.x;

    if (bid < 2048) {
        const size_t g8 = ((size_t)bid * 256 + tid) * 8;
        float4 a = *reinterpret_cast<const float4*>(hs + g8);
        float4 b = *reinterpret_cast<const float4*>(hs + g8 + 4);
        bf16x8 o;
        o[0] = (short)f2bf(a.x); o[1] = (short)f2bf(a.y);
        o[2] = (short)f2bf(a.z); o[3] = (short)f2bf(a.w);
        o[4] = (short)f2bf(b.x); o[5] = (short)f2bf(b.y);
        o[6] = (short)f2bf(b.z); o[7] = (short)f2bf(b.w);
        *reinterpret_cast<bf16x8*>(hs_bf + g8) = o;
        return;
    }

    const int i    = bid - 2048;          // 0..1023
    const int wsel = i >> 8;              // 0..3
    const float* W = (wsel == 0) ? W0 : (wsel == 1) ? W1 : (wsel == 2) ? W2 : W3;
    unsigned short* Wt = Wt_out + (size_t)wsel * 1024 * 1024;
    const int nt = i & 15;
    const int kt = (i >> 4) & 15;

#pragma unroll
    for (int r = 0; r < 4; ++r) {
        int kl = r * 16 + (tid >> 4);
        int nl = (tid & 15) * 4;
        float4 v = *reinterpret_cast<const float4*>(
            &W[(size_t)(kt * 64 + kl) * 1024 + nt * 64 + nl]);
        tile[kl][nl + 0] = v.x; tile[kl][nl + 1] = v.y;
        tile[kl][nl + 2] = v.z; tile[kl][nl + 3] = v.w;
    }
    __syncthreads();

    const int n  = tid >> 2;
    const int kc = (tid & 3) * 16;
    bf16x8 o0, o1;
#pragma unroll
    for (int i2 = 0; i2 < 8; ++i2) o0[i2] = (short)f2bf(tile[kc + i2][n]);
#pragma unroll
    for (int i2 = 0; i2 < 8; ++i2) o1[i2] = (short)f2bf(tile[kc + 8 + i2][n]);
    unsigned short* op = Wt + (size_t)(nt * 64 + n) * 1024 + kt * 64 + kc;
    *reinterpret_cast<bf16x8*>(op)     = o0;
    *reinterpret_cast<bf16x8*>(op + 8) = o1;
}

// ---------------------------------------------------------------------------
// bf16 MFMA GEMM (R10 K-loop + R19 LDS-staged epilogue): 128x128, BK=32,
// gload_lds(16B), double-buffered LDS, 2-phase, chunk-XOR swizzle, XCD-rect.
// MODE 0 (QKV): LDS-staged head-major epilogue (full-line stores).
// MODE 1: fp32 C + bias.
// ---------------------------------------------------------------------------
template <int MODE>
__global__ __launch_bounds__(256)
void gemm_bf16(const unsigned short* __restrict__ A,
               const unsigned short* __restrict__ Bt,
               const float* __restrict__ bias0, const float* __restrict__ bias1,
               const float* __restrict__ bias2,
               float* __restrict__ Cf,
               unsigned short* __restrict__ Qo, unsigned short* __restrict__ Ko,
               unsigned short* __restrict__ Vo,
               int M, int N, int K) {
    __shared__ unsigned short SM[4][128 * 32];   // A bufs [0..1], B bufs [2..3]

    int bx, by;
    {
        const int xcd = blockIdx.x & 7, i = blockIdx.x >> 3;
        if (MODE == 0) {            // grid 24x32 -> per-XCD 12x8 rectangle
            bx = (xcd >> 2) * 12 + i % 12;
            by = (xcd & 3) * 8 + i / 12;
        } else {                    // grid 8x32 -> per-XCD 4x8 rectangle
            bx = (xcd & 1) * 4 + i % 4;
            by = (xcd >> 1) * 8 + i / 4;
        }
    }
    const int tid  = threadIdx.x;
    const int bm   = by * 128;
    const int bn   = bx * 128;
    const int w    = tid >> 6;
    const int lane = tid & 63;
    const int lrow = lane & 15;
    const int lk   = lane >> 4;
    const int wm0  = (w >> 1) * 64;
    const int wn0  = (w & 1) * 64;

    const int boff0 = tid * 16;
    const int boff1 = 4096 + tid * 16;
    const int row0  = tid >> 2;
    const int row1  = 64 + row0;
    const int c     = tid & 3;
    const int sw0   = (c ^ ((row0 >> 1) & 3)) * 8;
    const int sw1   = (c ^ ((row1 >> 1) & 3)) * 8;

    const unsigned short* Ag = A  + (size_t)bm * K;
    const unsigned short* Bg = Bt + (size_t)bn * K;

    f32x4 acc[4][4];
#pragma unroll
    for (int i = 0; i < 4; ++i)
#pragma unroll
        for (int j = 0; j < 4; ++j) acc[i][j] = (f32x4){0.f, 0.f, 0.f, 0.f};

    const int NT = K / 32;
    gload16(Ag + (size_t)row0 * K + sw0, (char*)&SM[0][0] + boff0);
    gload16(Ag + (size_t)row1 * K + sw1, (char*)&SM[0][0] + boff1);
    gload16(Bg + (size_t)row0 * K + sw0, (char*)&SM[2][0] + boff0);
    gload16(Bg + (size_t)row1 * K + sw1, (char*)&SM[2][0] + boff1);
    __syncthreads();

    int buf = 0;
    for (int kt = 0; kt < NT; ++kt) {
        if (kt + 1 < NT) {
            const int k0 = (kt + 1) * 32;
            gload16(Ag + (size_t)row0 * K + k0 + sw0, (char*)&SM[buf ^ 1][0] + boff0);
            gload16(Ag + (size_t)row1 * K + k0 + sw1, (char*)&SM[buf ^ 1][0] + boff1);
            gload16(Bg + (size_t)row0 * K + k0 + sw0, (char*)&SM[2 + (buf ^ 1)][0] + boff0);
            gload16(Bg + (size_t)row1 * K + k0 + sw1, (char*)&SM[2 + (buf ^ 1)][0] + boff1);
        }

        bf16x8 af[4], bf[4];
#pragma unroll
        for (int mg = 0; mg < 4; ++mg) {
            const int r = wm0 + mg * 16 + lrow;
            af[mg] = *reinterpret_cast<const bf16x8*>(
                (char*)&SM[buf][0] + r * 64 + ((lk ^ ((r >> 1) & 3)) * 16));
        }
#pragma unroll
        for (int ng = 0; ng < 4; ++ng) {
            const int r = wn0 + ng * 16 + lrow;
            bf[ng] = *reinterpret_cast<const bf16x8*>(
                (char*)&SM[2 + buf][0] + r * 64 + ((lk ^ ((r >> 1) & 3)) * 16));
        }
#pragma unroll
        for (int mg = 0; mg < 4; ++mg)
#pragma unroll
            for (int ng = 0; ng < 4; ++ng)
                acc[mg][ng] = __builtin_amdgcn_mfma_f32_16x16x32_bf16(
                    af[mg], bf[ng], acc[mg][ng], 0, 0, 0);

        __syncthreads();
        buf ^= 1;
    }

    if (MODE == 0) {
        const int type = bn >> 10;                 // 0=Q 1=K 2=V (uniform/block)
        const int nloc = bn & 1023;
        const float* bias = (type == 0) ? bias0 : (type == 1) ? bias1 : bias2;
        unsigned short* dst = (type == 0) ? Qo : (type == 1) ? Ko : Vo;
        const float scale = (type == 0) ? (0.125f * 1.44269504088896f) : 1.0f;
        char* cst = (char*)&SM[0][0];              // 32KB C tile

        // deposit head-major tile [r][ctl], 16B-granule XOR swizzle
#pragma unroll
        for (int ng = 0; ng < 4; ++ng) {
            const int ctl = wn0 + ng * 16 + lrow;
            const float bv = bias[nloc + ctl];
            const int byte = ctl * 2;
#pragma unroll
            for (int mg = 0; mg < 4; ++mg) {
#pragma unroll
                for (int j = 0; j < 4; ++j) {
                    const int r = wm0 + mg * 16 + lk * 4 + j;
                    const int addr = r * 256 + (((byte >> 4) ^ (r & 7)) << 4) + (byte & 15);
                    *reinterpret_cast<unsigned short*>(cst + addr)
                        = f2bf((acc[mg][ng][j] + bv) * scale);
                }
            }
        }
        __syncthreads();

        // full-line stores: 8 lanes cover one 128B output line
        const int bb = bm >> 11;
        const int s0 = bm & 2047;
        const int h0 = nloc >> 6;
#pragma unroll
        for (int it = 0; it < 8; ++it) {
            const int hh = it >> 2;
            const int r  = (it & 3) * 32 + (tid >> 3);
            const int cc = tid & 7;
            const int addr = r * 256 + ((((hh * 8 + cc)) ^ (r & 7)) << 4);
            bf16x8 vals = *reinterpret_cast<const bf16x8*>(cst + addr);
            unsigned short* p = dst
                + ((size_t)(bb * 16 + h0 + hh) * SEQ + s0 + r) * 64 + cc * 8;
            *reinterpret_cast<bf16x8*>(p) = vals;
        }
    } else {
#pragma unroll
        for (int ng = 0; ng < 4; ++ng) {
            const int col = bn + wn0 + ng * 16 + lrow;
            const float bv = bias0[col];
#pragma unroll
            for (int mg = 0; mg < 4; ++mg) {
#pragma unroll
                for (int j = 0; j < 4; ++j) {
                    const int row = bm + wm0 + mg * 16 + lk * 4 + j;
                    Cf[(size_t)row * N + col] = acc[mg][ng][j] + bv;
                }
            }
        }
    }
}

// ---------------------------------------------------------------------------
// Transpose V: bf16 [B,H,S,64] -> bf16 [B,H,64,S] via 64x64 LDS tiles.
// ---------------------------------------------------------------------------
__global__ __launch_bounds__(256)
void vt_kernel(const unsigned short* __restrict__ Vh, unsigned short* __restrict__ Vt) {
    __shared__ unsigned short tile[64][72];
    const int bid = blockIdx.x;           // 0..1023
    const int st  = bid & 31;             // s-tile
    const int bh  = bid >> 5;             // 0..31
    const int s0  = st * 64;
    const int tid = threadIdx.x;

    const int sl = tid >> 2;
    const int dc = (tid & 3) * 16;
    const unsigned short* src = Vh + ((size_t)bh * SEQ + s0 + sl) * 64 + dc;
    *reinterpret_cast<bf16x8*>(&tile[sl][dc])     = *reinterpret_cast<const bf16x8*>(src);
    *reinterpret_cast<bf16x8*>(&tile[sl][dc + 8]) = *reinterpret_cast<const bf16x8*>(src + 8);
    __syncthreads();

    const int dl = tid >> 2;
    const int sc = (tid & 3) * 16;
    unsigned short tmp[16];
#pragma unroll
    for (int k2 = 0; k2 < 16; ++k2) tmp[k2] = tile[sc + k2][dl];
    unsigned short* dst = Vt + ((size_t)bh * 64 + dl) * SEQ + s0 + sc;
    *reinterpret_cast<bf16x8*>(dst)     = *reinterpret_cast<bf16x8*>(&tmp[0]);
    *reinterpret_cast<bf16x8*>(dst + 8) = *reinterpret_cast<bf16x8*>(&tmp[8]);
}

// ---------------------------------------------------------------------------
// Causal flash attention (R17 version, 45.7us proven): swapped-operand
// 32x32x16 MFMA, 128-key chunks with 2 subtiles/barrier, exp2 softmax with
// T13 defer-rescale, XCD head-grouping + constant-sum pairing.
// ---------------------------------------------------------------------------
__global__ __launch_bounds__(256)
void attn_mfma_kernel(const unsigned short* __restrict__ Qg,
                      const unsigned short* __restrict__ Kg,
                      const unsigned short* __restrict__ Vtg,
                      unsigned short* __restrict__ CTX) {
    __shared__ __align__(16) unsigned short Ks[2][2][64 * 64];
    __shared__ __align__(16) unsigned short Vt[2][2][64 * 64];

    const int bid = blockIdx.x;           // 0..511
    const int xcd = bid & 7;
    const int s   = bid >> 3;             // 0..63
    const int bh  = xcd * 4 + (s & 3);    // 4 heads per XCD
    const int k2  = s >> 2;               // 0..15
    const int rb  = (k2 < 8) ? k2 : (23 - k2);   // pair (k2,k2+8) -> (a,15-a)
    const int b  = bh >> 4;
    const int h  = bh & 15;
    const int r0 = rb * 128;
    const int tid  = threadIdx.x;
    const int w    = tid >> 6;
    const int lane = tid & 63;
    const int qcol = lane & 31;
    const int hlf  = lane >> 5;
    const int wr0  = r0 + w * 32;
    const int qrow = wr0 + qcol;

    const unsigned short* Kb = Kg + ((size_t)bh * SEQ) * DHEAD;
    const unsigned short* Vb = Vtg + ((size_t)bh * DHEAD) * SEQ;

    bf16x8 qf[4];
    {
        const unsigned short* qp = Qg + ((size_t)bh * SEQ + qrow) * DHEAD + hlf * 8;
#pragma unroll
        for (int ksub = 0; ksub < 4; ++ksub)
            qf[ksub] = *reinterpret_cast<const bf16x8*>(qp + ksub * 16);
    }

    f32x16 O0, O1;
#pragma unroll
    for (int r = 0; r < 16; ++r) { O0[r] = 0.f; O1[r] = 0.f; }
    float m = -1e30f, l = 0.f;

    const int srow = tid >> 2;
    const int c0   = (tid & 3) * 16;
    const int sb0  = srow * 128 + ((c0 * 2) ^ ((srow & 7) << 4));
    const int sb1  = srow * 128 + (((c0 + 8) * 2) ^ ((srow & 7) << 4));

    bf16x8 rk00, rk01, rk10, rk11, rv00, rv01, rv10, rv11;
    {
        const unsigned short* kp0 = Kb + (size_t)srow * DHEAD + c0;
        const unsigned short* kp1 = Kb + (size_t)(64 + srow) * DHEAD + c0;
        const unsigned short* vp  = Vb + (size_t)srow * SEQ + c0;
        rk00 = *reinterpret_cast<const bf16x8*>(kp0);
        rk01 = *reinterpret_cast<const bf16x8*>(kp0 + 8);
        rk10 = *reinterpret_cast<const bf16x8*>(kp1);
        rk11 = *reinterpret_cast<const bf16x8*>(kp1 + 8);
        rv00 = *reinterpret_cast<const bf16x8*>(vp);
        rv01 = *reinterpret_cast<const bf16x8*>(vp + 8);
        rv10 = *reinterpret_cast<const bf16x8*>(vp + 64);
        rv11 = *reinterpret_cast<const bf16x8*>(vp + 64 + 8);
    }

    const int nch = rb + 1;               // 128-key chunks
    for (int ch = 0; ch < nch; ++ch) {
        const int jc  = ch * 128;
        const int buf = ch & 1;
        {
            char* k0 = (char*)&Ks[buf][0][0];
            char* k1 = (char*)&Ks[buf][1][0];
            char* v0 = (char*)&Vt[buf][0][0];
            char* v1 = (char*)&Vt[buf][1][0];
            *reinterpret_cast<bf16x8*>(k0 + sb0) = rk00;
            *reinterpret_cast<bf16x8*>(k0 + sb1) = rk01;
            *reinterpret_cast<bf16x8*>(k1 + sb0) = rk10;
            *reinterpret_cast<bf16x8*>(k1 + sb1) = rk11;
            *reinterpret_cast<bf16x8*>(v0 + sb0) = rv00;
            *reinterpret_cast<bf16x8*>(v0 + sb1) = rv01;
            *reinterpret_cast<bf16x8*>(v1 + sb0) = rv10;
            *reinterpret_cast<bf16x8*>(v1 + sb1) = rv11;
        }
        __syncthreads();
        if (ch + 1 < nch) {
            const int j1 = jc + 128;
            const unsigned short* kp0 = Kb + (size_t)(j1 + srow) * DHEAD + c0;
            const unsigned short* kp1 = Kb + (size_t)(j1 + 64 + srow) * DHEAD + c0;
            const unsigned short* vp  = Vb + (size_t)srow * SEQ + j1 + c0;
            rk00 = *reinterpret_cast<const bf16x8*>(kp0);
            rk01 = *reinterpret_cast<const bf16x8*>(kp0 + 8);
            rk10 = *reinterpret_cast<const bf16x8*>(kp1);
            rk11 = *reinterpret_cast<const bf16x8*>(kp1 + 8);
            rv00 = *reinterpret_cast<const bf16x8*>(vp);
            rv01 = *reinterpret_cast<const bf16x8*>(vp + 8);
            rv10 = *reinterpret_cast<const bf16x8*>(vp + 64);
            rv11 = *reinterpret_cast<const bf16x8*>(vp + 64 + 8);
        }

#pragma unroll
        for (int st = 0; st < 2; ++st) {
            const int j0 = jc + st * 64;
            if (j0 <= wr0 + 31) {
                const char* KB = (const char*)&Ks[buf][st][0];
                const char* VB = (const char*)&Vt[buf][st][0];
                f32x16 S[2];
#pragma unroll
                for (int r = 0; r < 16; ++r) { S[0][r] = 0.f; S[1][r] = 0.f; }
                __builtin_amdgcn_s_setprio(1);
#pragma unroll
                for (int kb = 0; kb < 2; ++kb) {
                    const int key = kb * 32 + qcol;
#pragma unroll
                    for (int ksub = 0; ksub < 4; ++ksub) {
                        int boff = key * 128 + ((ksub * 32 + hlf * 16) ^ ((key & 7) << 4));
                        bf16x8 kf = *reinterpret_cast<const bf16x8*>(KB + boff);
                        S[kb] = __builtin_amdgcn_mfma_f32_32x32x16_bf16(
                            kf, qf[ksub], S[kb], 0, 0, 0);
                    }
                }
                __builtin_amdgcn_s_setprio(0);

                if (j0 + 63 > wr0) {
#pragma unroll
                    for (int kb = 0; kb < 2; ++kb)
#pragma unroll
                        for (int r = 0; r < 16; ++r) {
                            int ka = j0 + kb * 32 + (r & 3) + 8 * (r >> 2) + 4 * hlf;
                            if (ka > qrow) S[kb][r] = -1e30f;
                        }
                }

                float mx[8];
#pragma unroll
                for (int r = 0; r < 8; ++r)
                    mx[r] = fmaxf(fmaxf(S[0][r], S[0][r + 8]),
                                  fmaxf(S[1][r], S[1][r + 8]));
                float m01 = fmaxf(mx[0], mx[1]), m23 = fmaxf(mx[2], mx[3]);
                float m45 = fmaxf(mx[4], mx[5]), m67 = fmaxf(mx[6], mx[7]);
                float pm = fmaxf(fmaxf(m01, m23), fmaxf(m45, m67));
                pm = fmaxf(pm, __shfl_xor(pm, 32));

                if (!__all(pm <= m + 8.f)) {
                    float mnew = fmaxf(m, pm);
                    float cor  = __builtin_amdgcn_exp2f(m - mnew);
                    m = mnew;
                    l *= cor;
#pragma unroll
                    for (int r = 0; r < 16; ++r) { O0[r] *= cor; O1[r] *= cor; }
                }

                float l0 = 0.f, l1 = 0.f, l2 = 0.f, l3 = 0.f;
#pragma unroll
                for (int kb = 0; kb < 2; ++kb)
#pragma unroll
                    for (int r = 0; r < 16; r += 4) {
                        float p0 = __builtin_amdgcn_exp2f(S[kb][r + 0] - m);
                        float p1 = __builtin_amdgcn_exp2f(S[kb][r + 1] - m);
                        float p2 = __builtin_amdgcn_exp2f(S[kb][r + 2] - m);
                        float p3 = __builtin_amdgcn_exp2f(S[kb][r + 3] - m);
                        S[kb][r + 0] = p0; S[kb][r + 1] = p1;
                        S[kb][r + 2] = p2; S[kb][r + 3] = p3;
                        l0 += p0; l1 += p1; l2 += p2; l3 += p3;
                    }
                l += (l0 + l1) + (l2 + l3);

#pragma unroll
                for (int kc = 0; kc < 4; ++kc) {
                    const int kb = kc >> 1;
                    const int R0 = (kc & 1) * 8;
                    unsigned pa = cvt_pk_bf16(S[kb][R0 + 0], S[kb][R0 + 1]);
                    unsigned pc = cvt_pk_bf16(S[kb][R0 + 4], S[kb][R0 + 5]);
                    asm("v_permlane32_swap_b32 %0, %1" : "+v"(pa), "+v"(pc));
                    unsigned pb = cvt_pk_bf16(S[kb][R0 + 2], S[kb][R0 + 3]);
                    unsigned pd = cvt_pk_bf16(S[kb][R0 + 6], S[kb][R0 + 7]);
                    asm("v_permlane32_swap_b32 %0, %1" : "+v"(pb), "+v"(pd));
                    union { unsigned u[4]; bf16x8 v; } pf;
                    pf.u[0] = pa; pf.u[1] = pb; pf.u[2] = pc; pf.u[3] = pd;
                    __builtin_amdgcn_s_setprio(1);
#pragma unroll
                    for (int db = 0; db < 2; ++db) {
                        const int dim = db * 32 + qcol;
                        int boff = dim * 128 + ((kc * 32 + hlf * 16) ^ ((dim & 7) << 4));
                        bf16x8 vf = *reinterpret_cast<const bf16x8*>(VB + boff);
                        if (db == 0)
                            O0 = __builtin_amdgcn_mfma_f32_32x32x16_bf16(vf, pf.v, O0, 0, 0, 0);
                        else
                            O1 = __builtin_amdgcn_mfma_f32_32x32x16_bf16(vf, pf.v, O1, 0, 0, 0);
                    }
                    __builtin_amdgcn_s_setprio(0);
                }
            }
        }
    }

    l += __shfl_xor(l, 32);
    const float inv = 1.f / l;
    unsigned short* crow = CTX + ((size_t)(b * SEQ + qrow)) * DMODEL + h * DHEAD;
#pragma unroll
    for (int pq = 0; pq < 4; ++pq) {
        unsigned w0 = cvt_pk_bf16(O0[pq * 4 + 0] * inv, O0[pq * 4 + 1] * inv);
        unsigned w1 = cvt_pk_bf16(O0[pq * 4 + 2] * inv, O0[pq * 4 + 3] * inv);
        uint2 val; val.x = w0; val.y = w1;
        *reinterpret_cast<uint2*>(crow + 8 * pq + 4 * hlf) = val;
    }
#pragma unroll
    for (int pq = 0; pq < 4; ++pq) {
        unsigned w0 = cvt_pk_bf16(O1[pq * 4 + 0] * inv, O1[pq * 4 + 1] * inv);
        unsigned w1 = cvt_pk_bf16(O1[pq * 4 + 2] * inv, O1[pq * 4 + 3] * inv);
        uint2 val; val.x = w0; val.y = w1;
        *reinterpret_cast<uint2*>(crow + 32 + 8 * pq + 4 * hlf) = val;
    }
}

// ---------------------------------------------------------------------------
extern "C" void kernel_launch(void* const* d_in, const int* in_sizes, int n_in,
                              void* d_out, int out_size, void* d_ws, size_t ws_size,
                              hipStream_t stream) {
    const float* hs = (const float*)d_in[0];
    const float* Wq = (const float*)d_in[1];
    const float* bq = (const float*)d_in[2];
    const float* Wk = (const float*)d_in[3];
    const float* bk = (const float*)d_in[4];
    const float* Wv = (const float*)d_in[5];
    const float* bv = (const float*)d_in[6];
    const float* Wo = (const float*)d_in[7];
    const float* bo = (const float*)d_in[8];
    float* out = (float*)d_out;

    const size_t NTOK = (size_t)NBATCH * SEQ;        // 4096
    unsigned short* hs_bf  = (unsigned short*)d_ws;              // 8 MB
    unsigned short* Wqkv_t = hs_bf + NTOK * DMODEL;              // 6 MB [3072][1024]
    unsigned short* Wo_t   = Wqkv_t + 3072 * 1024;               // 2 MB [1024][1024]
    unsigned short* Qh     = Wo_t + 1024 * 1024;                 // 8 MB [B,H,S,64]
    unsigned short* Kh     = Qh + NTOK * DMODEL;                 // 8 MB
    unsigned short* Vh     = Kh + NTOK * DMODEL;                 // 8 MB [B,H,S,64]
    unsigned short* Vt     = Vh + NTOK * DMODEL;                 // 8 MB [B,H,64,S]
    unsigned short* Cb     = Vt + NTOK * DMODEL;                 // 8 MB ctx bf16

    prep_cast_kernel<<<3072, 256, 0, stream>>>(hs, Wq, Wk, Wv, Wo, hs_bf, Wqkv_t);

    gemm_bf16<0><<<768, 256, 0, stream>>>(hs_bf, Wqkv_t, bq, bk, bv,
                                          nullptr, Qh, Kh, Vh,
                                          (int)NTOK, 3072, DMODEL);

    vt_kernel<<<1024, 256, 0, stream>>>(Vh, Vt);

    attn_mfma_kernel<<<NBATCH * NHEADS * (SEQ / 128), 256, 0, stream>>>(Qh, Kh, Vt, Cb);

    gemm_bf16<1><<<256, 256, 0, stream>>>(Cb, Wo_t, bo, nullptr, nullptr,
                                          out, nullptr, nullptr, nullptr,
                                          (int)NTOK, DMODEL, DMODEL);
}